// Round 1
// baseline (36.043 us; speedup 1.0000x reference)
//
#include <hip/hip_runtime.h>
#include <hip/hip_bf16.h>

typedef __attribute__((ext_vector_type(8))) short short8;
typedef __attribute__((ext_vector_type(4))) float f32x4;

#define N_ROWS (16 * 4096)      // BATCH * N_EDGES
#define EDGE_DIM 64
#define NODE_DIM 32
#define NN 1024                 // NODE_DIM^2

__device__ __forceinline__ short f2bf(float f) {
    unsigned u = __builtin_bit_cast(unsigned, f);
    u += 0x7FFFu + ((u >> 16) & 1u);            // round-to-nearest-even
    return (short)(u >> 16);
}

// Pre-pack W [64,1024] f32 -> bf16 MFMA A-operand fragments in d_ws.
// frag id = chunk*2 + s   (chunk = 16-column group 0..63, s = K-step 0..1)
// Wb[(frag*64 + lane)*8 + t] = bf16(W[f, c]),
//   c = chunk*16 + (lane&15), f = s*32 + (lane>>4)*8 + t
__global__ void prep_W(const float* __restrict__ W, short* __restrict__ Wb) {
    int frag = blockIdx.x;          // 0..127
    int l = threadIdx.x;            // 0..63
    int c = (frag >> 1) * 16 + (l & 15);
    int fbase = (frag & 1) * 32 + ((l >> 4) * 8);
    short8 v;
#pragma unroll
    for (int t = 0; t < 8; ++t)
        v[t] = f2bf(W[(size_t)(fbase + t) * NN + c]);
    *reinterpret_cast<short8*>(Wb + ((size_t)frag * 64 + l) * 8) = v;
}

// One wave = 16 edge rows (MFMA N-dim). Per output row i (0..31): two 16x16
// A-column tiles (M-dim = A columns), K=64 in 2 steps -> 4 MFMA. Epilogue
// (bias+relu+matvec vs node) in f32 on accumulators; 2-step shfl_xor reduce.
__global__ __launch_bounds__(256) void mp_main(
    const float* __restrict__ node, const float* __restrict__ edge,
    const short* __restrict__ Wb, const float* __restrict__ bias,
    float* __restrict__ out) {
    __shared__ __align__(16) short ldsW[2048];       // 4 frags per iter = 4 KB
    __shared__ __align__(16) float ldsO[4][16][36];  // per-wave out staging

    const int tid = threadIdx.x;
    const int wid = tid >> 6;
    const int l   = tid & 63;
    const int l16 = l & 15;
    const int g   = l >> 4;                           // 16-lane group 0..3
    const int e   = blockIdx.x * 64 + wid * 16 + l16; // this lane's edge row

    // edge B-operand fragments (K-steps s=0,1): f = s*32 + g*8 + t
    short8 ef[2];
    const float* erow = edge + (size_t)e * EDGE_DIM;
#pragma unroll
    for (int s = 0; s < 2; ++s) {
        const float4* p = reinterpret_cast<const float4*>(erow + s * 32 + g * 8);
        float4 a = p[0], b2 = p[1];
        short8 v;
        v[0] = f2bf(a.x);  v[1] = f2bf(a.y);  v[2] = f2bf(a.z);  v[3] = f2bf(a.w);
        v[4] = f2bf(b2.x); v[5] = f2bf(b2.y); v[6] = f2bf(b2.z); v[7] = f2bf(b2.w);
        ef[s] = v;
    }

    // node values this lane ever needs: j = p*16 + g*4 + r  (f32, loaded once)
    float nval[8];
    const float* nrow = node + (size_t)e * NODE_DIM;
#pragma unroll
    for (int p = 0; p < 2; ++p)
#pragma unroll
        for (int r = 0; r < 4; ++r)
            nval[p * 4 + r] = nrow[p * 16 + g * 4 + r];

    for (int i = 0; i < 32; ++i) {
        __syncthreads();
        // stage this i's 4 W fragments (4 KB) -> LDS, shared by all 4 waves
        *reinterpret_cast<short8*>(&ldsW[tid * 8]) =
            *reinterpret_cast<const short8*>(Wb + (size_t)i * 2048 + tid * 8);
        __syncthreads();
        short8 wf0 = *reinterpret_cast<const short8*>(&ldsW[(0 * 64 + l) * 8]);
        short8 wf1 = *reinterpret_cast<const short8*>(&ldsW[(1 * 64 + l) * 8]);
        short8 wf2 = *reinterpret_cast<const short8*>(&ldsW[(2 * 64 + l) * 8]);
        short8 wf3 = *reinterpret_cast<const short8*>(&ldsW[(3 * 64 + l) * 8]);

        float bb[8];
#pragma unroll
        for (int c2 = 0; c2 < 2; ++c2)
#pragma unroll
            for (int r = 0; r < 4; ++r)
                bb[c2 * 4 + r] = bias[i * 32 + c2 * 16 + g * 4 + r];

        f32x4 acc0 = {0.f, 0.f, 0.f, 0.f};
        f32x4 acc1 = {0.f, 0.f, 0.f, 0.f};
        // D[c_local, e_local]: rows = A columns, cols = edges
        acc0 = __builtin_amdgcn_mfma_f32_16x16x32_bf16(wf0, ef[0], acc0, 0, 0, 0);
        acc0 = __builtin_amdgcn_mfma_f32_16x16x32_bf16(wf1, ef[1], acc0, 0, 0, 0);
        acc1 = __builtin_amdgcn_mfma_f32_16x16x32_bf16(wf2, ef[0], acc1, 0, 0, 0);
        acc1 = __builtin_amdgcn_mfma_f32_16x16x32_bf16(wf3, ef[1], acc1, 0, 0, 0);

        // epilogue: bias + relu + multiply by node, reduce over the 32 j's
        // lane's rows: chunk0 -> j = g*4+r, chunk1 -> j = 16+g*4+r
        float partial = 0.f;
#pragma unroll
        for (int r = 0; r < 4; ++r) {
            float v0 = acc0[r] + bb[r];
            v0 = fmaxf(v0, 0.f);
            partial += v0 * nval[r];
            float v1 = acc1[r] + bb[4 + r];
            v1 = fmaxf(v1, 0.f);
            partial += v1 * nval[4 + r];
        }
        partial += __shfl_xor(partial, 16);
        partial += __shfl_xor(partial, 32);
        if (l < 16) ldsO[wid][l][i] = partial;   // msg[e = l, i]
    }

    // coalesced store: wave's 16x32 output tile is contiguous in `out`
    const int eo = l >> 2;
    const int i0 = (l & 3) * 8;
    float4 v0 = *reinterpret_cast<const float4*>(&ldsO[wid][eo][i0]);
    float4 v1 = *reinterpret_cast<const float4*>(&ldsO[wid][eo][i0 + 4]);
    size_t obase = ((size_t)(blockIdx.x * 64 + wid * 16 + eo)) * NODE_DIM + i0;
    *reinterpret_cast<float4*>(out + obase) = v0;
    *reinterpret_cast<float4*>(out + obase + 4) = v1;
}

extern "C" void kernel_launch(void* const* d_in, const int* in_sizes, int n_in,
                              void* d_out, int out_size, void* d_ws, size_t ws_size,
                              hipStream_t stream) {
    const float* node = (const float*)d_in[0];  // [16,4096,32] f32
    const float* edge = (const float*)d_in[1];  // [16,4096,64] f32
    const float* W    = (const float*)d_in[2];  // [64,1024] f32
    const float* bias = (const float*)d_in[3];  // [1024] f32
    float* out = (float*)d_out;                 // [16,4096,32] f32
    short* Wb = (short*)d_ws;                   // 128 KB bf16 fragment-packed W

    prep_W<<<dim3(128), dim3(64), 0, stream>>>(W, Wb);
    mp_main<<<dim3(N_ROWS / 64), dim3(256), 0, stream>>>(node, edge, Wb, bias, out);
}

// Round 2
// 30.198 us; speedup vs baseline: 1.1935x; 1.1935x over previous
//
#include <hip/hip_runtime.h>
#include <hip/hip_bf16.h>

typedef __attribute__((ext_vector_type(8))) short short8;
typedef __attribute__((ext_vector_type(4))) float f32x4;
typedef unsigned int u32;

#define NROWS 65536             // BATCH * N_EDGES
#define EDGE_DIM 64
#define NODE_DIM 32
#define NN 1024                 // NODE_DIM^2

__device__ __forceinline__ short f2bf(float f) {
    unsigned u = __builtin_bit_cast(unsigned, f);
    u += 0x7FFFu + ((u >> 16) & 1u);            // round-to-nearest-even
    return (short)(u >> 16);
}

// async 16B global->LDS copy (dest = wave-uniform base + lane*16)
__device__ __forceinline__ void gload_lds16(const void* g, void* l) {
    __builtin_amdgcn_global_load_lds(
        (const __attribute__((address_space(1))) u32*)g,
        (__attribute__((address_space(3))) u32*)l, 16, 0, 0);
}

// Pre-pack W [64,1024] f32 -> bf16 MFMA A-operand fragments in d_ws.
// frag id = chunk*2 + s (chunk = 16-col group 0..63, s = K-step 0..1)
// Wb[(frag*64 + lane)*8 + t] = bf16(W[s*32 + (lane>>4)*8 + t, chunk*16 + (lane&15)])
__global__ void prep_W(const float* __restrict__ W, short* __restrict__ Wb) {
    int frag = blockIdx.x * 4 + (threadIdx.x >> 6);   // 32 blocks x 4 frags
    int l = threadIdx.x & 63;
    int c = (frag >> 1) * 16 + (l & 15);
    int fb = (frag & 1) * 32 + ((l >> 4) * 8);
    short8 v;
#pragma unroll
    for (int t = 0; t < 8; ++t)
        v[t] = f2bf(W[(size_t)(fb + t) * NN + c]);
    *reinterpret_cast<short8*>(Wb + ((size_t)frag * 64 + l) * 8) = v;
}

// One wave = 32 edges (two 16-edge MFMA column groups sharing W fragments).
// 8 rounds x 4 i's; W staged double-buffered via global_load_lds (16 KB/round).
// Bias enters as the MFMA C-operand. Epilogue: relu+matvec in f32, 2x shfl_xor.
__global__ __launch_bounds__(256, 2) void mp_main(
    const float* __restrict__ node, const float* __restrict__ edge,
    const short* __restrict__ Wb, const float* __restrict__ bias,
    float* __restrict__ out) {
    __shared__ __align__(16) short ldsW[2][8192];    // 2 x 16 KB (16 frags/round)
    __shared__ __align__(16) float ldsO[4][32][33];  // per-wave 32x32 out tile

    const int tid = threadIdx.x;
    const int wid = tid >> 6;
    const int l   = tid & 63;
    const int l16 = l & 15;
    const int g   = l >> 4;
    const int eb  = blockIdx.x * 128 + wid * 32;     // wave's first edge row

    // ---- per-lane inputs: edge fragments (bf16) + node values (f32) ----
    short8 ef[2][2];   // [edge-group][k-step]
    float  nv[2][8];   // [edge-group][j-slot]: j = p*16 + g*4 + r -> nv[eg][p*4+r]
#pragma unroll
    for (int eg = 0; eg < 2; ++eg) {
        const float* erow = edge + (size_t)(eb + eg * 16 + l16) * EDGE_DIM;
#pragma unroll
        for (int s = 0; s < 2; ++s) {
            float4 a = *reinterpret_cast<const float4*>(erow + s * 32 + g * 8);
            float4 b = *reinterpret_cast<const float4*>(erow + s * 32 + g * 8 + 4);
            short8 v;
            v[0] = f2bf(a.x); v[1] = f2bf(a.y); v[2] = f2bf(a.z); v[3] = f2bf(a.w);
            v[4] = f2bf(b.x); v[5] = f2bf(b.y); v[6] = f2bf(b.z); v[7] = f2bf(b.w);
            ef[eg][s] = v;
        }
        const float* nrow = node + (size_t)(eb + eg * 16 + l16) * NODE_DIM;
#pragma unroll
        for (int p = 0; p < 2; ++p) {
            float4 n4 = *reinterpret_cast<const float4*>(nrow + p * 16 + g * 4);
            nv[eg][p * 4 + 0] = n4.x; nv[eg][p * 4 + 1] = n4.y;
            nv[eg][p * 4 + 2] = n4.z; nv[eg][p * 4 + 3] = n4.w;
        }
    }

    // ---- stage round 0 (frags [0,16) = 16 KB), 4 issues of 4 KB/block ----
#pragma unroll
    for (int k = 0; k < 4; ++k)
        gload_lds16(Wb + (size_t)(k * 256 + tid) * 8,
                    &ldsW[0][(size_t)k * 2048 + wid * 512]);

    for (int r = 0; r < 8; ++r) {
        __syncthreads();   // drains vmcnt(0): buf[r&1] staged; prev round's reads done
        if (r < 7) {       // overlap: stage next round into the other buffer
            const short* src = Wb + (size_t)(r + 1) * 8192;
#pragma unroll
            for (int k = 0; k < 4; ++k)
                gload_lds16(src + (size_t)(k * 256 + tid) * 8,
                            &ldsW[(r + 1) & 1][(size_t)k * 2048 + wid * 512]);
        }
        const short* wl = ldsW[r & 1];
#pragma unroll
        for (int q = 0; q < 4; ++q) {
            const int i = r * 4 + q;
            short8 wf0 = *reinterpret_cast<const short8*>(&wl[((q * 4 + 0) * 64 + l) * 8]);
            short8 wf1 = *reinterpret_cast<const short8*>(&wl[((q * 4 + 1) * 64 + l) * 8]);
            short8 wf2 = *reinterpret_cast<const short8*>(&wl[((q * 4 + 2) * 64 + l) * 8]);
            short8 wf3 = *reinterpret_cast<const short8*>(&wl[((q * 4 + 3) * 64 + l) * 8]);
            // bias as C-init: C row = g*4+r (column-independent)
            f32x4 bc0 = *reinterpret_cast<const f32x4*>(bias + i * 32 + g * 4);
            f32x4 bc1 = *reinterpret_cast<const f32x4*>(bias + i * 32 + 16 + g * 4);

            f32x4 a00 = __builtin_amdgcn_mfma_f32_16x16x32_bf16(wf0, ef[0][0], bc0, 0, 0, 0);
            a00 = __builtin_amdgcn_mfma_f32_16x16x32_bf16(wf1, ef[0][1], a00, 0, 0, 0);
            f32x4 a01 = __builtin_amdgcn_mfma_f32_16x16x32_bf16(wf2, ef[0][0], bc1, 0, 0, 0);
            a01 = __builtin_amdgcn_mfma_f32_16x16x32_bf16(wf3, ef[0][1], a01, 0, 0, 0);
            f32x4 a10 = __builtin_amdgcn_mfma_f32_16x16x32_bf16(wf0, ef[1][0], bc0, 0, 0, 0);
            a10 = __builtin_amdgcn_mfma_f32_16x16x32_bf16(wf1, ef[1][1], a10, 0, 0, 0);
            f32x4 a11 = __builtin_amdgcn_mfma_f32_16x16x32_bf16(wf2, ef[1][0], bc1, 0, 0, 0);
            a11 = __builtin_amdgcn_mfma_f32_16x16x32_bf16(wf3, ef[1][1], a11, 0, 0, 0);

            float p0 = 0.f, p1 = 0.f;
#pragma unroll
            for (int rr = 0; rr < 4; ++rr) {
                p0 += fmaxf(a00[rr], 0.f) * nv[0][rr];
                p0 += fmaxf(a01[rr], 0.f) * nv[0][4 + rr];
                p1 += fmaxf(a10[rr], 0.f) * nv[1][rr];
                p1 += fmaxf(a11[rr], 0.f) * nv[1][4 + rr];
            }
            p0 += __shfl_xor(p0, 16); p0 += __shfl_xor(p0, 32);
            p1 += __shfl_xor(p1, 16); p1 += __shfl_xor(p1, 32);
            if (g < 2) ldsO[wid][g * 16 + l16][i] = g ? p1 : p0;   // msg[edge, i]
        }
    }

    // ---- coalesced store: wave tile = 32 rows x 128 B contiguous ----
#pragma unroll
    for (int q = 0; q < 4; ++q) {
        int idx = q * 64 + l;            // 16B-chunk index in the 4 KB tile
        int row = idx >> 3;
        int col = (idx & 7) * 4;
        float4 v = *reinterpret_cast<const float4*>(&ldsO[wid][row][col]);
        *reinterpret_cast<float4*>(out + (size_t)eb * NODE_DIM + (size_t)idx * 4) = v;
    }
}

extern "C" void kernel_launch(void* const* d_in, const int* in_sizes, int n_in,
                              void* d_out, int out_size, void* d_ws, size_t ws_size,
                              hipStream_t stream) {
    const float* node = (const float*)d_in[0];  // [16,4096,32] f32
    const float* edge = (const float*)d_in[1];  // [16,4096,64] f32
    const float* W    = (const float*)d_in[2];  // [64,1024] f32
    const float* bias = (const float*)d_in[3];  // [1024] f32
    float* out = (float*)d_out;                 // [16,4096,32] f32
    short* Wb = (short*)d_ws;                   // 128 KB bf16 fragment-packed W

    prep_W<<<dim3(32), dim3(256), 0, stream>>>(W, Wb);
    mp_main<<<dim3(NROWS / 128), dim3(256), 0, stream>>>(node, edge, Wb, bias, out);
}